// Round 10
// baseline (173.277 us; speedup 1.0000x reference)
//
#include <hip/hip_runtime.h>
#include <hip/hip_bf16.h>
#include <math.h>

// Problem shape (fixed by setup_inputs): B=128, S=20, C=32000
#define NB 128
#define NS 20
#define NC 32000
#define NROWS (NB * NS)            // 2560
#define CPR 4                      // chunks per row (quarter rows)
#define NCHUNK (NROWS * CPR)       // 10240 chunks of 8000 elements
#define CHUNK_F4 2000              // float4 per chunk
#define NBLOCKS 2048               // 8 blocks/CU exactly, all co-resident

// min with lane^1 / lane^2 via DPP quad_perm (pure VALU, no LDS)
static __device__ __forceinline__ float fmin_x1(float x) {
    int t = __builtin_amdgcn_update_dpp(0, __float_as_int(x), 0xB1, 0xf, 0xf, true); // [1,0,3,2]
    return fminf(x, __int_as_float(t));
}
static __device__ __forceinline__ float fmin_x2(float x) {
    int t = __builtin_amdgcn_update_dpp(0, __float_as_int(x), 0x4E, 0xf, 0xf, true); // [2,3,0,1]
    return fminf(x, __int_as_float(t));
}
// min with lane^4 / ^8 / ^16 via ds_swizzle bitmode (1 LDS-pipe op each)
static __device__ __forceinline__ float fmin_x4(float x) {
    int t = __builtin_amdgcn_ds_swizzle(__float_as_int(x), 0x101F);
    return fminf(x, __int_as_float(t));
}
static __device__ __forceinline__ float fmin_x8(float x) {
    int t = __builtin_amdgcn_ds_swizzle(__float_as_int(x), 0x201F);
    return fminf(x, __int_as_float(t));
}
static __device__ __forceinline__ float fmin_x16(float x) {
    int t = __builtin_amdgcn_ds_swizzle(__float_as_int(x), 0x401F);
    return fminf(x, __int_as_float(t));
}
static __device__ __forceinline__ float readlane_f(float x, int lane) {
    return __int_as_float(__builtin_amdgcn_readlane(__float_as_int(x), lane));
}

// ---------------------------------------------------------------------------
// Mega kernel, 2048 co-resident blocks:
//   blocks 0..127 : fused gather + restricted-softmax cost + wave-parallel
//                   Hungarian (readlane + DPP/swizzle butterfly), THEN join
//                   the chunk steal loop.
//   blocks 128+   : chunk steal loop from t=0.
// Steal loop: thread 0 grabs a quarter-row chunk via RELAXED agent-scope
// fetch_add (no acquire/release, no fences -> none of the r6/r8 per-block
// L2 writeback/invalidate storms). Each chunk's partial (max, sumexp) is
// written with plain stores; the dispatch boundary before final_kernel is
// the only synchronization. Chunk values are executor-independent, so the
// output is deterministic despite nondeterministic assignment.
// ---------------------------------------------------------------------------
__global__ __launch_bounds__(256) void mega_kernel(
        const float* __restrict__ outputs,
        const int* __restrict__ gold,
        const float* __restrict__ weight,
        unsigned* __restrict__ ctr,      // zeroed via hipMemsetAsync pre-launch
        int* __restrict__ match_col,     // [NROWS] assigned 0-based column per row
        float* __restrict__ sub_ws,      // [NROWS*NS] raw gathered logits
        float* __restrict__ pm,          // [NCHUNK] chunk max
        float* __restrict__ ps) {        // [NCHUNK] chunk sumexp (rel. to pm)

    __shared__ float smx[4], ssm[4];
    __shared__ unsigned cur;

    if (blockIdx.x < NB) {
        // =================== fused cost + wave Hungarian ===================
        const int b = blockIdx.x;
        const int* g = gold + b * NS;
        __shared__ float cst[NS * NS];   // sub logits, then cost, in place
        __shared__ float lzs[NS];

        // phase 1: gather outputs[b, i, gold[b, j]] + save raw logits to ws
        for (int e = threadIdx.x; e < NS * NS; e += 256) {
            int i = e / NS, j = e - i * NS;
            float x = outputs[(size_t)(b * NS + i) * NC + g[j]];
            cst[e] = x;
            sub_ws[(size_t)(b * NS + i) * NS + j] = x;
        }
        __syncthreads();
        // phase 2: per-row restricted logsumexp over the 20 gold columns
        if (threadIdx.x < NS) {
            int i = threadIdx.x;
            float mx = cst[i * NS];
#pragma unroll
            for (int j = 1; j < NS; ++j) mx = fmaxf(mx, cst[i * NS + j]);
            float s = 0.f;
#pragma unroll
            for (int j = 0; j < NS; ++j) s += __expf(cst[i * NS + j] - mx);
            lzs[i] = mx + __logf(s);
        }
        __syncthreads();
        // phase 3: cost = -(x - lz) * w[gold[j]]  (BIG replaces inf)
        for (int e = threadIdx.x; e < NS * NS; e += 256) {
            int i = e / NS, j = e - i * NS;
            float c = -(cst[e] - lzs[i]) * weight[g[j]];
            if (isinf(c)) c = 1e8f;
            cst[e] = c;
        }
        __syncthreads();

        if (threadIdx.x < 64) {
            // ---- wave 0: shortest-augmenting-path Hungarian, f32 ----
            // Lane j (1..20) owns column j: p_j matched row (0=free),
            // up_j=u[p_j]; lane 0 carries phase row i / u[i].
            const int lane = threadIdx.x;
            const float FINF = INFINITY;
            float up_j = 0.f, v_j = 0.f;
            int p_j = 0, way_j = 0;
            const bool is_col = (lane >= 1 && lane <= NS);

            for (int i = 1; i <= NS; ++i) {
                if (lane == 0) { p_j = i; up_j = 0.f; }   // p[0]=i, u[i]=0
                int j0 = 0;
                float minv_j = FINF;
                bool used_j = false;
                while (true) {
                    int pp = __builtin_amdgcn_readlane(p_j, j0);   // p[j0]
                    if (pp == 0) break;           // free column reached
                    if (lane == j0) used_j = true;
                    float upp = readlane_f(up_j, j0);              // u[p[j0]]
                    float cv = cst[is_col ? (pp - 1) * NS + (lane - 1) : 0];
                    if (is_col && !used_j) {
                        float curv = cv - upp - v_j;
                        if (curv < minv_j) { minv_j = curv; way_j = j0; }  // strict <
                    }
                    float cand = (is_col && !used_j) ? minv_j : FINF;
                    // 5-step min over lanes 0..31: 2 DPP + 3 swizzle
                    float mval = fmin_x16(fmin_x8(fmin_x4(fmin_x2(fmin_x1(cand)))));
                    // lowest-lane argmin = np.argmin tie-break
                    unsigned long long bal = __ballot(cand == mval) & 0xFFFFFFFFull;
                    int j1 = __ffsll(bal) - 1;
                    float delta = mval;           // uniform on lanes 0..31
                    if (used_j) { up_j += delta; v_j -= delta; }
                    else if (is_col) minv_j -= delta;
                    j0 = j1;
                }
                while (j0 != 0) {                 // augment along way[]
                    int   j1   = __builtin_amdgcn_readlane(way_j, j0);
                    int   pj1  = __builtin_amdgcn_readlane(p_j, j1);
                    float upj1 = readlane_f(up_j, j1);
                    if (lane == j0) { p_j = pj1; up_j = upj1; }
                    j0 = j1;
                }
            }
            // ans[p[j]-1] = j-1
            if (is_col && p_j != 0) {
                match_col[b * NS + (p_j - 1)] = lane - 1;
            }
        }
        // waves 1..3 wait here while wave 0 solves; then all join the stream
        __syncthreads();
    }

    // =================== chunk steal loop (all blocks) ===================
    for (;;) {
        __syncthreads();   // protect cur + smx/ssm reuse across iterations
        if (threadIdx.x == 0) {
            cur = __hip_atomic_fetch_add(ctr, 1u, __ATOMIC_RELAXED,
                                         __HIP_MEMORY_SCOPE_AGENT);
        }
        __syncthreads();
        unsigned c = cur;
        if (c >= (unsigned)NCHUNK) break;     // uniform exit
        const int row = c >> 2, q = c & 3;
        const float4* rp = (const float4*)outputs
                         + (size_t)row * (NC / 4) + q * CHUNK_F4;

        float m = -INFINITY;
        float s = 0.f;
        // 4-deep unrolled region: float4 indices 0..1023
        {
            int i0 = threadIdx.x;
            float4 a = rp[i0];
            float4 bq = rp[i0 + 256];
            float4 cq = rp[i0 + 512];
            float4 d = rp[i0 + 768];
            float m4 = fmaxf(fmaxf(fmaxf(a.x, a.y), fmaxf(a.z, a.w)),
                             fmaxf(fmaxf(bq.x, bq.y), fmaxf(bq.z, bq.w)));
            m4 = fmaxf(m4, fmaxf(fmaxf(fmaxf(cq.x, cq.y), fmaxf(cq.z, cq.w)),
                                 fmaxf(fmaxf(d.x, d.y), fmaxf(d.z, d.w))));
            m = m4;
            s = __expf(a.x - m) + __expf(a.y - m) + __expf(a.z - m) + __expf(a.w - m)
              + __expf(bq.x - m) + __expf(bq.y - m) + __expf(bq.z - m) + __expf(bq.w - m)
              + __expf(cq.x - m) + __expf(cq.y - m) + __expf(cq.z - m) + __expf(cq.w - m)
              + __expf(d.x - m) + __expf(d.y - m) + __expf(d.z - m) + __expf(d.w - m);
        }
        // remainder: float4 indices 1024..1999
        for (int idx = 1024 + threadIdx.x; idx < CHUNK_F4; idx += 256) {
            float4 x = rp[idx];
            float m4 = fmaxf(fmaxf(x.x, x.y), fmaxf(x.z, x.w));
            float nm = fmaxf(m, m4);
            s = s * __expf(m - nm)
              + __expf(x.x - nm) + __expf(x.y - nm)
              + __expf(x.z - nm) + __expf(x.w - nm);
            m = nm;
        }
        // wave reduce (64 lanes)
        for (int off = 1; off < 64; off <<= 1) {
            float om = __shfl_xor(m, off);
            float os = __shfl_xor(s, off);
            float nm = fmaxf(m, om);
            s = s * __expf(m - nm) + os * __expf(om - nm);
            m = nm;
        }
        int wid = threadIdx.x >> 6;
        if ((threadIdx.x & 63) == 0) { smx[wid] = m; ssm[wid] = s; }
        __syncthreads();
        if (threadIdx.x == 0) {
            float M = smx[0], S = ssm[0];
            for (int w = 1; w < 4; ++w) {
                float om = smx[w], os = ssm[w];
                float nm = fmaxf(M, om);
                S = S * __expf(M - nm) + os * __expf(om - nm);
                M = nm;
            }
            pm[c] = M;        // plain stores; dispatch boundary syncs
            ps[c] = S;
        }
    }
}

// ---------------------------------------------------------------------------
// Final reduce: merge 4 chunk-partials per row (fixed order -> deterministic),
// then masked-mean NLL. Everything L2-hot. f64 tree reduce.
// ---------------------------------------------------------------------------
__global__ __launch_bounds__(256) void final_kernel(
        const int* __restrict__ match_col,
        const float* __restrict__ sub_ws,
        const float* __restrict__ pm,
        const float* __restrict__ ps,
        const float* __restrict__ weight,
        const int* __restrict__ gold,
        const unsigned char* __restrict__ mask,
        float* __restrict__ out) {
    double nsum = 0.0, msum = 0.0;
    for (int r = threadIdx.x; r < NROWS; r += 256) {
        // merge the 4 quarter-row partials in fixed order
        float M = pm[r * CPR], S = ps[r * CPR];
#pragma unroll
        for (int q = 1; q < CPR; ++q) {
            float om = pm[r * CPR + q], os = ps[r * CPR + q];
            float nm = fmaxf(M, om);
            S = S * __expf(M - nm) + os * __expf(om - nm);
            M = nm;
        }
        float lz = M + __logf(S);
        int b = r / NS;
        int col = match_col[r];
        float x = sub_ws[(size_t)r * NS + col];          // outputs[b,i,match]
        float w = weight[gold[b * NS + col]];            // weight[match]
        float nll = -(x - lz) * w;
        float mk = mask[r] ? 1.f : 0.f;
        nsum += (double)(nll * mk);
        msum += (double)mk;
    }
    for (int off = 1; off < 64; off <<= 1) {
        nsum += __shfl_xor(nsum, off);
        msum += __shfl_xor(msum, off);
    }
    __shared__ double sn[4], sm[4];
    int wid = threadIdx.x >> 6;
    if ((threadIdx.x & 63) == 0) { sn[wid] = nsum; sm[wid] = msum; }
    __syncthreads();
    if (threadIdx.x == 0) {
        double N = 0.0, M = 0.0;
        for (int w = 0; w < 4; ++w) { N += sn[w]; M += sm[w]; }
        out[0] = (float)(N / (M + 1e-8));
    }
}

// ---------------------------------------------------------------------------
extern "C" void kernel_launch(void* const* d_in, const int* in_sizes, int n_in,
                              void* d_out, int out_size, void* d_ws, size_t ws_size,
                              hipStream_t stream) {
    const float* outputs        = (const float*)d_in[0];          // [B,S,C] f32
    const int*   gold           = (const int*)d_in[1];            // [B,S] i32
    const unsigned char* mask   = (const unsigned char*)d_in[2];  // [B,S] bool
    const float* weight         = (const float*)d_in[3];          // [C] f32
    float* out = (float*)d_out;

    // workspace layout
    char* ws = (char*)d_ws;
    unsigned* ctr     = (unsigned*)ws;                                 // 16 B
    int*   match_col  = (int*)(ws + 16);                               // NROWS
    float* sub_ws     = (float*)(ws + 16 + (size_t)NROWS * 4);         // NROWS*NS
    float* pm         = (float*)(ws + 16 + (size_t)NROWS * 4
                                 + (size_t)NROWS * NS * 4);            // NCHUNK
    float* ps         = pm + NCHUNK;                                   // NCHUNK

    hipMemsetAsync(ctr, 0, sizeof(unsigned), stream);
    mega_kernel<<<NBLOCKS, 256, 0, stream>>>(outputs, gold, weight, ctr,
                                             match_col, sub_ws, pm, ps);
    final_kernel<<<1, 256, 0, stream>>>(match_col, sub_ws, pm, ps, weight,
                                        gold, mask, out);
}

// Round 11
// 69.081 us; speedup vs baseline: 2.5083x; 2.5083x over previous
//
#include <hip/hip_runtime.h>
#include <hip/hip_bf16.h>
#include <math.h>

// Problem shape (fixed by setup_inputs): B=128, S=20, C=32000
#define NB 128
#define NS 20
#define NC 32000
#define NROWS (NB * NS)            // 2560
#define NBLOCKS 1280               // exactly 5 blocks/CU (256 CUs), one phase
// Row plan (total 2560, 320/XCD, classes uniform mod 8):
//   bid   0..127 : solver for batch bid, then 1 row: 2432+bid
//   bid 128..255 : 3 rows: (bid-128)*3 ..                  (rows    0..383)
//   bid 256..1279: 2 rows: 384+(bid-256)*2 ..              (rows  384..2431)

// min with lane^1 / lane^2 via DPP quad_perm (pure VALU, no LDS)
static __device__ __forceinline__ float fmin_x1(float x) {
    int t = __builtin_amdgcn_update_dpp(0, __float_as_int(x), 0xB1, 0xf, 0xf, true); // [1,0,3,2]
    return fminf(x, __int_as_float(t));
}
static __device__ __forceinline__ float fmin_x2(float x) {
    int t = __builtin_amdgcn_update_dpp(0, __float_as_int(x), 0x4E, 0xf, 0xf, true); // [2,3,0,1]
    return fminf(x, __int_as_float(t));
}
// min with lane^4 / ^8 / ^16 via ds_swizzle bitmode (1 LDS-pipe op each)
static __device__ __forceinline__ float fmin_x4(float x) {
    int t = __builtin_amdgcn_ds_swizzle(__float_as_int(x), 0x101F);
    return fminf(x, __int_as_float(t));
}
static __device__ __forceinline__ float fmin_x8(float x) {
    int t = __builtin_amdgcn_ds_swizzle(__float_as_int(x), 0x201F);
    return fminf(x, __int_as_float(t));
}
static __device__ __forceinline__ float fmin_x16(float x) {
    int t = __builtin_amdgcn_ds_swizzle(__float_as_int(x), 0x401F);
    return fminf(x, __int_as_float(t));
}
static __device__ __forceinline__ float readlane_f(float x, int lane) {
    return __int_as_float(__builtin_amdgcn_readlane(__float_as_int(x), lane));
}

// ---------------------------------------------------------------------------
// Mega kernel. ZERO cross-block sync (fences r6 / acq-rel r8 / even relaxed
// contended RMW r10 all collapse the stream on gfx950). 1280 blocks = 5/CU
// exactly; every block carries ~equal work (solver counts as ~1 row).
// ---------------------------------------------------------------------------
__global__ __launch_bounds__(256) void mega_kernel(
        const float* __restrict__ outputs,
        const int* __restrict__ gold,
        const float* __restrict__ weight,
        int* __restrict__ match_col,     // [NROWS] assigned 0-based column per row
        float* __restrict__ sub_ws,      // [NROWS*NS] raw gathered logits
        float* __restrict__ logZ) {      // [NROWS]

    __shared__ float smx[4], ssm[4];
    const int bid = blockIdx.x;

    if (bid < NB) {
        // =================== fused cost + wave Hungarian ===================
        const int b = bid;
        const int* g = gold + b * NS;
        __shared__ float cst[NS * NS];   // sub logits, then cost, in place
        __shared__ float lzs[NS];

        // phase 1: gather outputs[b, i, gold[b, j]] + save raw logits to ws
        for (int e = threadIdx.x; e < NS * NS; e += 256) {
            int i = e / NS, j = e - i * NS;
            float x = outputs[(size_t)(b * NS + i) * NC + g[j]];
            cst[e] = x;
            sub_ws[(size_t)(b * NS + i) * NS + j] = x;
        }
        __syncthreads();
        // phase 2: per-row restricted logsumexp over the 20 gold columns
        if (threadIdx.x < NS) {
            int i = threadIdx.x;
            float mx = cst[i * NS];
#pragma unroll
            for (int j = 1; j < NS; ++j) mx = fmaxf(mx, cst[i * NS + j]);
            float s = 0.f;
#pragma unroll
            for (int j = 0; j < NS; ++j) s += __expf(cst[i * NS + j] - mx);
            lzs[i] = mx + __logf(s);
        }
        __syncthreads();
        // phase 3: cost = -(x - lz) * w[gold[j]]  (BIG replaces inf)
        for (int e = threadIdx.x; e < NS * NS; e += 256) {
            int i = e / NS, j = e - i * NS;
            float c = -(cst[e] - lzs[i]) * weight[g[j]];
            if (isinf(c)) c = 1e8f;
            cst[e] = c;
        }
        __syncthreads();

        if (threadIdx.x < 64) {
            // ---- wave 0: shortest-augmenting-path Hungarian, f32 ----
            // Lane j (1..20) owns column j: p_j matched row (0=free),
            // up_j=u[p_j]; lane 0 carries phase row i / u[i].
            const int lane = threadIdx.x;
            const float FINF = INFINITY;
            float up_j = 0.f, v_j = 0.f;
            int p_j = 0, way_j = 0;
            const bool is_col = (lane >= 1 && lane <= NS);

            for (int i = 1; i <= NS; ++i) {
                if (lane == 0) { p_j = i; up_j = 0.f; }   // p[0]=i, u[i]=0
                int j0 = 0;
                float minv_j = FINF;
                bool used_j = false;
                while (true) {
                    int pp = __builtin_amdgcn_readlane(p_j, j0);   // p[j0]
                    if (pp == 0) break;           // free column reached
                    if (lane == j0) used_j = true;
                    float upp = readlane_f(up_j, j0);              // u[p[j0]]
                    float cv = cst[is_col ? (pp - 1) * NS + (lane - 1) : 0];
                    if (is_col && !used_j) {
                        float curv = cv - upp - v_j;
                        if (curv < minv_j) { minv_j = curv; way_j = j0; }  // strict <
                    }
                    float cand = (is_col && !used_j) ? minv_j : FINF;
                    // 5-step min over lanes 0..31: 2 DPP + 3 swizzle
                    float mval = fmin_x16(fmin_x8(fmin_x4(fmin_x2(fmin_x1(cand)))));
                    // lowest-lane argmin = np.argmin tie-break
                    unsigned long long bal = __ballot(cand == mval) & 0xFFFFFFFFull;
                    int j1 = __ffsll(bal) - 1;
                    float delta = mval;           // uniform on lanes 0..31
                    if (used_j) { up_j += delta; v_j -= delta; }
                    else if (is_col) minv_j -= delta;
                    j0 = j1;
                }
                while (j0 != 0) {                 // augment along way[]
                    int   j1   = __builtin_amdgcn_readlane(way_j, j0);
                    int   pj1  = __builtin_amdgcn_readlane(p_j, j1);
                    float upj1 = readlane_f(up_j, j1);
                    if (lane == j0) { p_j = pj1; up_j = upj1; }
                    j0 = j1;
                }
            }
            // ans[p[j]-1] = j-1
            if (is_col && p_j != 0) {
                match_col[b * NS + (p_j - 1)] = lane - 1;
            }
        }
        __syncthreads();   // all waves rejoin before the LSE row
    }

    // =================== LSE rows (static balanced plan) ===================
    int r0, nr;
    if (bid < 128)      { r0 = 2432 + bid;          nr = 1; }
    else if (bid < 256) { r0 = (bid - 128) * 3;     nr = 3; }
    else                { r0 = 384 + (bid - 256) * 2; nr = 2; }

    for (int rr = 0; rr < nr; ++rr) {
        const int row = r0 + rr;
        const float4* rp = (const float4*)(outputs + (size_t)row * NC);
        const int n4 = NC / 4;                  // 8000
        const int nfull = (n4 / 1024) * 1024;   // 7168: 4-deep unrolled region

        float m = -INFINITY;
        float s = 0.f;
        // 4 independent coalesced loads in flight per thread
        for (int base = 0; base < nfull; base += 1024) {
            int i0 = base + threadIdx.x;
            float4 a = rp[i0];
            float4 bq = rp[i0 + 256];
            float4 c = rp[i0 + 512];
            float4 d = rp[i0 + 768];
            float m4 = fmaxf(fmaxf(fmaxf(a.x, a.y), fmaxf(a.z, a.w)),
                             fmaxf(fmaxf(bq.x, bq.y), fmaxf(bq.z, bq.w)));
            m4 = fmaxf(m4, fmaxf(fmaxf(fmaxf(c.x, c.y), fmaxf(c.z, c.w)),
                                 fmaxf(fmaxf(d.x, d.y), fmaxf(d.z, d.w))));
            float nm = fmaxf(m, m4);
            float sl = __expf(a.x - nm) + __expf(a.y - nm)
                     + __expf(a.z - nm) + __expf(a.w - nm);
            sl += __expf(bq.x - nm) + __expf(bq.y - nm)
                + __expf(bq.z - nm) + __expf(bq.w - nm);
            sl += __expf(c.x - nm) + __expf(c.y - nm)
                + __expf(c.z - nm) + __expf(c.w - nm);
            sl += __expf(d.x - nm) + __expf(d.y - nm)
                + __expf(d.z - nm) + __expf(d.w - nm);
            s = s * __expf(m - nm) + sl;
            m = nm;
        }
        // remainder (832 float4s), single-load loop
        for (int idx = nfull + threadIdx.x; idx < n4; idx += 256) {
            float4 x = rp[idx];
            float m4 = fmaxf(fmaxf(x.x, x.y), fmaxf(x.z, x.w));
            float nm = fmaxf(m, m4);
            s = s * __expf(m - nm)
              + __expf(x.x - nm) + __expf(x.y - nm)
              + __expf(x.z - nm) + __expf(x.w - nm);
            m = nm;
        }
        for (int off = 1; off < 64; off <<= 1) {
            float om = __shfl_xor(m, off);
            float os = __shfl_xor(s, off);
            float nm = fmaxf(m, om);
            s = s * __expf(m - nm) + os * __expf(om - nm);
            m = nm;
        }
        __syncthreads();   // protect smx/ssm reuse across rr iterations
        int wid = threadIdx.x >> 6;
        if ((threadIdx.x & 63) == 0) { smx[wid] = m; ssm[wid] = s; }
        __syncthreads();
        if (threadIdx.x == 0) {
            float M = smx[0], S = ssm[0];
            for (int w = 1; w < 4; ++w) {
                float om = smx[w], os = ssm[w];
                float nm = fmaxf(M, om);
                S = S * __expf(M - nm) + os * __expf(om - nm);
                M = nm;
            }
            logZ[row] = M + __logf(S);
        }
    }
}

// ---------------------------------------------------------------------------
// Final masked-mean NLL reduce — everything L2-hot (sub_ws, logZ, match_col).
// Deterministic tree reduce, f64 accumulation. 512 threads: 5 rows/thread.
// ---------------------------------------------------------------------------
__global__ __launch_bounds__(512) void final_kernel(
        const int* __restrict__ match_col,
        const float* __restrict__ sub_ws,
        const float* __restrict__ logZ,
        const float* __restrict__ weight,
        const int* __restrict__ gold,
        const unsigned char* __restrict__ mask,
        float* __restrict__ out) {
    double nsum = 0.0, msum = 0.0;
    for (int r = threadIdx.x; r < NROWS; r += 512) {
        int b = r / NS;
        int col = match_col[r];
        float x = sub_ws[(size_t)r * NS + col];          // outputs[b,i,match]
        float w = weight[gold[b * NS + col]];            // weight[match]
        float nll = -(x - logZ[r]) * w;
        float mk = mask[r] ? 1.f : 0.f;
        nsum += (double)(nll * mk);
        msum += (double)mk;
    }
    for (int off = 1; off < 64; off <<= 1) {
        nsum += __shfl_xor(nsum, off);
        msum += __shfl_xor(msum, off);
    }
    __shared__ double sn[8], sm[8];
    int wid = threadIdx.x >> 6;
    if ((threadIdx.x & 63) == 0) { sn[wid] = nsum; sm[wid] = msum; }
    __syncthreads();
    if (threadIdx.x == 0) {
        double N = 0.0, M = 0.0;
        for (int w = 0; w < 8; ++w) { N += sn[w]; M += sm[w]; }
        out[0] = (float)(N / (M + 1e-8));
    }
}

// ---------------------------------------------------------------------------
extern "C" void kernel_launch(void* const* d_in, const int* in_sizes, int n_in,
                              void* d_out, int out_size, void* d_ws, size_t ws_size,
                              hipStream_t stream) {
    const float* outputs        = (const float*)d_in[0];          // [B,S,C] f32
    const int*   gold           = (const int*)d_in[1];            // [B,S] i32
    const unsigned char* mask   = (const unsigned char*)d_in[2];  // [B,S] bool
    const float* weight         = (const float*)d_in[3];          // [C] f32
    float* out = (float*)d_out;

    // workspace layout
    char* ws = (char*)d_ws;
    int*   match_col = (int*)ws;                                   // NROWS
    float* logZ      = (float*)(ws + (size_t)NROWS * 4);           // NROWS
    float* sub_ws    = (float*)(ws + (size_t)NROWS * 8);           // NROWS*NS

    mega_kernel<<<NBLOCKS, 256, 0, stream>>>(outputs, gold, weight,
                                             match_col, sub_ws, logZ);
    final_kernel<<<1, 512, 0, stream>>>(match_col, sub_ws, logZ, weight, gold,
                                        mask, out);
}